// Round 1
// baseline (1531.915 us; speedup 1.0000x reference)
//
#include <hip/hip_runtime.h>
#include <math.h>

#define F 1024
#define NROWS 8192
#define NELEM (NROWS * F)

// ---------------- damp = 0.01 * mean(x^2), deterministic 2-stage ----------------
__global__ void sumsq_partial_kernel(const float* __restrict__ x, float* __restrict__ partial) {
    __shared__ float sdata[256];
    int tid = threadIdx.x;
    int base = blockIdx.x * 4096;
    float s = 0.f;
    for (int i = tid; i < 4096; i += 256) {
        float v = x[base + i];
        s = fmaf(v, v, s);
    }
    sdata[tid] = s;
    __syncthreads();
    for (int off = 128; off > 0; off >>= 1) {
        if (tid < off) sdata[tid] += sdata[tid + off];
        __syncthreads();
    }
    if (tid == 0) partial[blockIdx.x] = sdata[0];
}

__global__ void finish_damp_kernel(const float* __restrict__ partial, float* __restrict__ scal) {
    __shared__ float sdata[256];
    int tid = threadIdx.x;
    float s = 0.f;
    for (int i = tid; i < 2048; i += 256) s += partial[i];
    sdata[tid] = s;
    __syncthreads();
    for (int off = 128; off > 0; off >>= 1) {
        if (tid < off) sdata[tid] += sdata[tid + off];
        __syncthreads();
    }
    if (tid == 0) {
        float mean = sdata[0] / (float)NELEM;
        scal[1] = 0.01f * mean;   // damp
    }
}

// ---------------- H = X^T X + damp*I   (M=N=1024, K=8192) ----------------
__global__ __launch_bounds__(256) void syrk_kernel(const float* __restrict__ X,
                                                   float* __restrict__ H,
                                                   const float* __restrict__ scal) {
    __shared__ float LA[16][64];
    __shared__ float LB[16][64];
    int tx = threadIdx.x, ty = threadIdx.y;          // 16 x 16
    int t = ty * 16 + tx;
    int i0 = blockIdx.y * 64, j0 = blockIdx.x * 64;
    int lk = t >> 4;            // 0..15
    int lc = (t & 15) << 2;     // 0,4,..,60
    float acc[4][4] = {};
    for (int k0 = 0; k0 < NROWS; k0 += 16) {
        int r = (k0 + lk) * F;
        float4 a4 = *(const float4*)&X[r + i0 + lc];
        float4 b4 = *(const float4*)&X[r + j0 + lc];
        __syncthreads();
        *(float4*)&LA[lk][lc] = a4;
        *(float4*)&LB[lk][lc] = b4;
        __syncthreads();
#pragma unroll
        for (int kk = 0; kk < 16; ++kk) {
            float4 a = *(const float4*)&LA[kk][ty << 2];
            float4 b = *(const float4*)&LB[kk][tx << 2];
            float av[4] = {a.x, a.y, a.z, a.w};
            float bv[4] = {b.x, b.y, b.z, b.w};
#pragma unroll
            for (int rr = 0; rr < 4; ++rr)
#pragma unroll
                for (int cc = 0; cc < 4; ++cc)
                    acc[rr][cc] = fmaf(av[rr], bv[cc], acc[rr][cc]);
        }
    }
    float damp = scal[1];
#pragma unroll
    for (int rr = 0; rr < 4; ++rr) {
        int i = i0 + (ty << 2) + rr;
#pragma unroll
        for (int cc = 0; cc < 4; ++cc) {
            int j = j0 + (tx << 2) + cc;
            float v = acc[rr][cc];
            if (i == j) v += damp;
            H[i * F + j] = v;
        }
    }
}

// ---------------- power iteration: lambda_max estimate ----------------
__global__ void init_v_kernel(float* __restrict__ v) {
    int i = blockIdx.x * 256 + threadIdx.x;
    if (i < F) v[i] = 1.0f;
}

__global__ void matvec_kernel(const float* __restrict__ H, const float* __restrict__ v,
                              float* __restrict__ y) {
    __shared__ float sdata[256];
    int row = blockIdx.x, tid = threadIdx.x;
    float s = 0.f;
    for (int j = tid; j < F; j += 256) s = fmaf(H[row * F + j], v[j], s);
    sdata[tid] = s;
    __syncthreads();
    for (int off = 128; off > 0; off >>= 1) {
        if (tid < off) sdata[tid] += sdata[tid + off];
        __syncthreads();
    }
    if (tid == 0) y[row] = sdata[0];
}

__global__ void normalize_kernel(const float* __restrict__ y, float* __restrict__ v,
                                 float* __restrict__ scal) {
    __shared__ float sdata[256];
    __shared__ float lam;
    int tid = threadIdx.x;
    float s = 0.f;
    for (int i = tid; i < F; i += 256) {
        float t = y[i];
        s = fmaf(t, t, s);
    }
    sdata[tid] = s;
    __syncthreads();
    for (int off = 128; off > 0; off >>= 1) {
        if (tid < off) sdata[tid] += sdata[tid + off];
        __syncthreads();
    }
    if (tid == 0) {
        lam = sqrtf(sdata[0]);
        scal[2] = lam;
        scal[3] = 1.0f / (1.02f * lam);   // Newton-Schulz scale c
    }
    __syncthreads();
    float il = 1.0f / lam;
    for (int i = tid; i < F; i += 256) v[i] = y[i] * il;
}

// ---------------- Newton-Schulz ----------------
__global__ void init_X_kernel(float* __restrict__ A, const float* __restrict__ scal) {
    int idx = blockIdx.x * 256 + threadIdx.x;   // grid covers F*F
    int i = idx >> 10, j = idx & (F - 1);
    A[idx] = (i == j) ? scal[3] : 0.0f;
}

// mode 0: C = A @ B     mode 1: C = 2*D - A @ B
__global__ __launch_bounds__(256) void gemm_nn_kernel(const float* __restrict__ A,
                                                      const float* __restrict__ Bm,
                                                      float* __restrict__ C,
                                                      const float* __restrict__ D,
                                                      int mode) {
    __shared__ float LA[16][64];   // [k][i]
    __shared__ float LB[16][64];   // [k][j]
    int tx = threadIdx.x, ty = threadIdx.y;
    int t = ty * 16 + tx;
    int i0 = blockIdx.y * 64, j0 = blockIdx.x * 64;
    // A-tile load indices: 64 rows x 16 k, float4 along k
    int aii = t >> 2;              // 0..63
    int akq = (t & 3) << 2;        // 0,4,8,12
    // B-tile load indices: 16 k-rows x 64 cols, float4 along j
    int bkk = t >> 4;              // 0..15
    int bjq = (t & 15) << 2;       // 0..60
    float acc[4][4] = {};
    for (int k0 = 0; k0 < F; k0 += 16) {
        float4 a4 = *(const float4*)&A[(i0 + aii) * F + k0 + akq];
        float4 b4 = *(const float4*)&Bm[(k0 + bkk) * F + j0 + bjq];
        __syncthreads();
        LA[akq + 0][aii] = a4.x;
        LA[akq + 1][aii] = a4.y;
        LA[akq + 2][aii] = a4.z;
        LA[akq + 3][aii] = a4.w;
        *(float4*)&LB[bkk][bjq] = b4;
        __syncthreads();
#pragma unroll
        for (int kk = 0; kk < 16; ++kk) {
            float4 a = *(const float4*)&LA[kk][ty << 2];
            float4 b = *(const float4*)&LB[kk][tx << 2];
            float av[4] = {a.x, a.y, a.z, a.w};
            float bv[4] = {b.x, b.y, b.z, b.w};
#pragma unroll
            for (int rr = 0; rr < 4; ++rr)
#pragma unroll
                for (int cc = 0; cc < 4; ++cc)
                    acc[rr][cc] = fmaf(av[rr], bv[cc], acc[rr][cc]);
        }
    }
#pragma unroll
    for (int rr = 0; rr < 4; ++rr) {
        int i = i0 + (ty << 2) + rr;
#pragma unroll
        for (int cc = 0; cc < 4; ++cc) {
            int j = j0 + (tx << 2) + cc;
            float v = acc[rr][cc];
            if (mode == 1) v = 2.0f * D[i * F + j] - v;
            C[i * F + j] = v;
        }
    }
}

// ---------------- finalize: hinv -> out, perm -> out ----------------
__global__ void finalize_kernel(const float* __restrict__ A, float* __restrict__ out) {
    int idx = blockIdx.x * 256 + threadIdx.x;
    if (idx < F * F) out[idx] = A[idx];
    else if (idx < F * F + F) out[idx] = (float)(idx - F * F);
}

extern "C" void kernel_launch(void* const* d_in, const int* in_sizes, int n_in,
                              void* d_out, int out_size, void* d_ws, size_t ws_size,
                              hipStream_t stream) {
    const float* x = (const float*)d_in[0];
    float* ws = (float*)d_ws;
    float* scal    = ws;                 // [1]=damp [2]=lambda [3]=c
    float* partial = ws + 64;            // 2048
    float* H  = ws + 4096;               // 1M floats
    float* A  = H + F * F;               // 1M
    float* B  = A + F * F;               // 1M
    float* v  = B + F * F;               // 1024
    float* y  = v + F;                   // 1024
    float* out = (float*)d_out;
    float* R = out;                      // reuse d_out as GEMM scratch

    sumsq_partial_kernel<<<2048, 256, 0, stream>>>(x, partial);
    finish_damp_kernel<<<1, 256, 0, stream>>>(partial, scal);

    dim3 grid16(16, 16), blk16(16, 16);
    syrk_kernel<<<grid16, blk16, 0, stream>>>(x, H, scal);

    init_v_kernel<<<4, 256, 0, stream>>>(v);
    for (int it = 0; it < 12; ++it) {
        matvec_kernel<<<F, 256, 0, stream>>>(H, v, y);
        normalize_kernel<<<1, 256, 0, stream>>>(y, v, scal);
    }

    init_X_kernel<<<(F * F) / 256, 256, 0, stream>>>(A, scal);
    float* Xc = A;
    float* Xn = B;
    for (int it = 0; it < 8; ++it) {
        gemm_nn_kernel<<<grid16, blk16, 0, stream>>>(H, Xc, R, nullptr, 0);  // R = H @ Xc
        gemm_nn_kernel<<<grid16, blk16, 0, stream>>>(Xc, R, Xn, Xc, 1);      // Xn = 2Xc - Xc@R
        float* tmp = Xc; Xc = Xn; Xn = tmp;
    }

    finalize_kernel<<<(F * F + F + 255) / 256, 256, 0, stream>>>(Xc, out);
}

// Round 2
// 478.355 us; speedup vs baseline: 3.2025x; 3.2025x over previous
//
#include <hip/hip_runtime.h>
#include <math.h>

#define F 1024
#define NROWS 8192
#define NELEM (NROWS * F)

typedef unsigned short ushort_t;
typedef short bf16x8 __attribute__((ext_vector_type(8)));
typedef float f32x4 __attribute__((ext_vector_type(4)));
typedef unsigned short ushort8 __attribute__((ext_vector_type(8)));

__device__ __forceinline__ ushort_t f2bf(float f) {
  unsigned u = __float_as_uint(f);
  unsigned r = (u + 0x7fffu + ((u >> 16) & 1u)) >> 16;
  return (ushort_t)r;
}
__device__ __forceinline__ float bf2f(ushort_t b) {
  return __uint_as_float(((unsigned)b) << 16);
}

typedef const __attribute__((address_space(1))) unsigned int* gas_ptr;
typedef __attribute__((address_space(3))) unsigned int* las_ptr;
__device__ __forceinline__ void gload16(const void* g, const void* l) {
  __builtin_amdgcn_global_load_lds((gas_ptr)(unsigned long long)g,
                                   (las_ptr)(unsigned int)(unsigned long long)l,
                                   16, 0, 0);
}

// ---------------- damp = 0.01 * mean(x^2) ----------------
__global__ void sumsq_partial_kernel(const float* __restrict__ x, float* __restrict__ partial) {
    __shared__ float sdata[256];
    int tid = threadIdx.x;
    int base = blockIdx.x * 4096;
    float s = 0.f;
    for (int i = tid; i < 4096; i += 256) {
        float v = x[base + i];
        s = fmaf(v, v, s);
    }
    sdata[tid] = s;
    __syncthreads();
    for (int off = 128; off > 0; off >>= 1) {
        if (tid < off) sdata[tid] += sdata[tid + off];
        __syncthreads();
    }
    if (tid == 0) partial[blockIdx.x] = sdata[0];
}

__global__ void finish_damp_kernel(const float* __restrict__ partial, float* __restrict__ scal) {
    __shared__ float sdata[256];
    int tid = threadIdx.x;
    float s = 0.f;
    for (int i = tid; i < 2048; i += 256) s += partial[i];
    sdata[tid] = s;
    __syncthreads();
    for (int off = 128; off > 0; off >>= 1) {
        if (tid < off) sdata[tid] += sdata[tid + off];
        __syncthreads();
    }
    if (tid == 0) {
        float mean = sdata[0] / (float)NELEM;
        scal[1] = 0.01f * mean;   // damp
    }
}

// ---------------- transpose+convert: X (8192x1024 f32) -> XT hi/lo (1024x8192 bf16) ----------------
__global__ __launch_bounds__(256) void tconv_kernel(const float* __restrict__ x,
                                                    ushort_t* __restrict__ xthi,
                                                    ushort_t* __restrict__ xtlo) {
    __shared__ ushort_t th[64][68];
    __shared__ ushort_t tl[64][68];
    int c0 = blockIdx.x * 64;   // col of X (0..1023)
    int r0 = blockIdx.y * 64;   // row of X (0..8191)
    int tid = threadIdx.x;
#pragma unroll
    for (int i = 0; i < 4; ++i) {
        int q = tid + 256 * i;
        int r = q >> 4;            // 0..63
        int cq = (q & 15) << 2;    // 0..60
        float4 vx = *(const float4*)&x[(size_t)(r0 + r) * 1024 + c0 + cq];
        float vv[4] = {vx.x, vx.y, vx.z, vx.w};
#pragma unroll
        for (int j = 0; j < 4; ++j) {
            ushort_t h = f2bf(vv[j]);
            ushort_t l = f2bf(vv[j] - bf2f(h));
            th[r][cq + j] = h;
            tl[r][cq + j] = l;
        }
    }
    __syncthreads();
#pragma unroll
    for (int i = 0; i < 2; ++i) {
        int q = tid + 256 * i;
        int c = q >> 3;            // 0..63
        int rq = (q & 7) << 3;     // 0..56
        ushort8 oh, ol;
#pragma unroll
        for (int j = 0; j < 8; ++j) {
            oh[j] = th[rq + j][c];
            ol[j] = tl[rq + j][c];
        }
        *(ushort8*)&xthi[(size_t)(c0 + c) * 8192 + r0 + rq] = oh;
        *(ushort8*)&xtlo[(size_t)(c0 + c) * 8192 + r0 + rq] = ol;
    }
}

// ---------------- MFMA GEMM (split-bf16), C_partial[z] = Arows * Brows^T ----------------
// A'[m][k] = Ahi/lo[row0A + m][k];  B'[k][n] = Bhi/lo[row0B + n][k]  (B given by rows = symmetric input or XT)
// Output P[z][m][n], grid (8,8,z=4), 256 threads, tile 128x128, k-tile 32.
__device__ __forceinline__ void stage_tile(const ushort_t* __restrict__ gp, int ld, int row0,
                                           int kk, const ushort_t* smembase, int w, int lane) {
#pragma unroll
    for (int half = 0; half < 2; ++half) {
        int s = half * 256 + (w << 6) + lane;
        int r = s >> 2, pos = s & 3;
        int kc = pos ^ ((r >> 1) & 3);
        const ushort_t* ga = gp + (size_t)(row0 + r) * ld + kk + (kc << 3);
        gload16(ga, smembase + ((half * 256 + (w << 6)) << 3));
    }
}

__global__ __launch_bounds__(256, 2) void mfma_gemm_kernel(
    const ushort_t* __restrict__ Ahi, const ushort_t* __restrict__ Alo,
    const ushort_t* __restrict__ Bhi, const ushort_t* __restrict__ Blo,
    int lda, int ldb, int kchunk, float* __restrict__ P, int terms)
{
    __shared__ ushort_t smem[16384];   // 4 tensors x 4096 ushorts (8KB each)
    int tid = threadIdx.x, lane = tid & 63, w = tid >> 6;
    int wm = w >> 1, wn = w & 1;
    int arow0 = blockIdx.y * 128, brow0 = blockIdx.x * 128;
    int k0 = blockIdx.z * kchunk;
    int lr = lane & 15, cg = lane >> 4;
    int laneoff = lr * 32 + ((cg ^ ((lr >> 1) & 3)) << 3);

    f32x4 zero4 = {0.f, 0.f, 0.f, 0.f};
    f32x4 acc[4][4];
#pragma unroll
    for (int a = 0; a < 4; ++a)
#pragma unroll
        for (int b = 0; b < 4; ++b) acc[a][b] = zero4;

    int ktiles = kchunk >> 5;
    for (int kt = 0; kt < ktiles; ++kt) {
        int kk = k0 + (kt << 5);
        __syncthreads();
        stage_tile(Ahi, lda, arow0, kk, smem + 0, w, lane);
        stage_tile(Bhi, ldb, brow0, kk, smem + 8192, w, lane);
        if (terms == 3) {
            stage_tile(Alo, lda, arow0, kk, smem + 4096, w, lane);
            stage_tile(Blo, ldb, brow0, kk, smem + 12288, w, lane);
        }
        __syncthreads();

        bf16x8 ah[4], bh[4], al[4], bl[4];
#pragma unroll
        for (int fx = 0; fx < 4; ++fx) {
            int ao = ((wm << 6) + (fx << 4)) * 32;
            int bo = ((wn << 6) + (fx << 4)) * 32;
            ah[fx] = *(const bf16x8*)&smem[0 + ao + laneoff];
            bh[fx] = *(const bf16x8*)&smem[8192 + bo + laneoff];
            if (terms == 3) {
                al[fx] = *(const bf16x8*)&smem[4096 + ao + laneoff];
                bl[fx] = *(const bf16x8*)&smem[12288 + bo + laneoff];
            }
        }
#pragma unroll
        for (int fm = 0; fm < 4; ++fm)
#pragma unroll
            for (int fn = 0; fn < 4; ++fn) {
                acc[fm][fn] = __builtin_amdgcn_mfma_f32_16x16x32_bf16(ah[fm], bh[fn], acc[fm][fn], 0, 0, 0);
                if (terms == 3) {
                    acc[fm][fn] = __builtin_amdgcn_mfma_f32_16x16x32_bf16(ah[fm], bl[fn], acc[fm][fn], 0, 0, 0);
                    acc[fm][fn] = __builtin_amdgcn_mfma_f32_16x16x32_bf16(al[fm], bh[fn], acc[fm][fn], 0, 0, 0);
                }
            }
    }

    float* Pz = P + (size_t)blockIdx.z * (1024u * 1024u);
    int rb = arow0 + (wm << 6), cb = brow0 + (wn << 6);
#pragma unroll
    for (int fm = 0; fm < 4; ++fm)
#pragma unroll
        for (int fn = 0; fn < 4; ++fn)
#pragma unroll
            for (int rr = 0; rr < 4; ++rr) {
                int row = rb + fm * 16 + cg * 4 + rr;
                int col = cb + fn * 16 + lr;
                Pz[(size_t)row * 1024 + col] = acc[fm][fn][rr];
            }
}

// ---------------- reduce kernels (split-K sum + fused bf16-split convert) ----------------
__global__ void reduceH_kernel(const float* __restrict__ P, float* __restrict__ H,
                               ushort_t* __restrict__ Hhi, ushort_t* __restrict__ Hlo,
                               const float* __restrict__ scal) {
    int idx4 = blockIdx.x * 256 + threadIdx.x;   // over 262144 float4
    const float4* p = (const float4*)P;
    float4 s = p[idx4];
    float4 s1 = p[idx4 + 262144], s2 = p[idx4 + 524288], s3 = p[idx4 + 786432];
    float v[4] = {s.x + s1.x + s2.x + s3.x, s.y + s1.y + s2.y + s3.y,
                  s.z + s1.z + s2.z + s3.z, s.w + s1.w + s2.w + s3.w};
    float damp = scal[1];
    int base = idx4 * 4;
#pragma unroll
    for (int j = 0; j < 4; ++j) {
        int i = base + j;
        float val = v[j];
        if ((i >> 10) == (i & 1023)) val += damp;
        H[i] = val;
        ushort_t h = f2bf(val);
        Hhi[i] = h;
        Hlo[i] = f2bf(val - bf2f(h));
    }
}

__global__ void reduceS_kernel(const float* __restrict__ P,
                               ushort_t* __restrict__ Shi, ushort_t* __restrict__ Slo) {
    int idx4 = blockIdx.x * 256 + threadIdx.x;
    const float4* p = (const float4*)P;
    float4 s = p[idx4];
    float4 s1 = p[idx4 + 262144], s2 = p[idx4 + 524288], s3 = p[idx4 + 786432];
    float v[4] = {s.x + s1.x + s2.x + s3.x, s.y + s1.y + s2.y + s3.y,
                  s.z + s1.z + s2.z + s3.z, s.w + s1.w + s2.w + s3.w};
    int base = idx4 * 4;
#pragma unroll
    for (int j = 0; j < 4; ++j) {
        float val = v[j];
        ushort_t h = f2bf(val);
        Shi[base + j] = h;
        Slo[base + j] = f2bf(val - bf2f(h));
    }
}

__global__ void reduceX_kernel(const float* __restrict__ P, const float* __restrict__ Xc,
                               float* __restrict__ Xn,
                               ushort_t* __restrict__ Xnhi, ushort_t* __restrict__ Xnlo) {
    int idx4 = blockIdx.x * 256 + threadIdx.x;
    const float4* p = (const float4*)P;
    const float4* xc4 = (const float4*)Xc;
    float4 s = p[idx4];
    float4 s1 = p[idx4 + 262144], s2 = p[idx4 + 524288], s3 = p[idx4 + 786432];
    float4 xc = xc4[idx4];
    float v[4] = {2.f * xc.x - (s.x + s1.x + s2.x + s3.x),
                  2.f * xc.y - (s.y + s1.y + s2.y + s3.y),
                  2.f * xc.z - (s.z + s1.z + s2.z + s3.z),
                  2.f * xc.w - (s.w + s1.w + s2.w + s3.w)};
    int base = idx4 * 4;
#pragma unroll
    for (int j = 0; j < 4; ++j) {
        float val = v[j];
        Xn[base + j] = val;
        ushort_t h = f2bf(val);
        Xnhi[base + j] = h;
        Xnlo[base + j] = f2bf(val - bf2f(h));
    }
}

// ---------------- power iteration ----------------
__global__ void init_v_kernel(float* __restrict__ v) {
    int i = blockIdx.x * 256 + threadIdx.x;
    if (i < F) v[i] = 1.0f;
}

__global__ void matvec_kernel(const float* __restrict__ H, const float* __restrict__ v,
                              float* __restrict__ y) {
    __shared__ float sdata[256];
    int row = blockIdx.x, tid = threadIdx.x;
    float s = 0.f;
    for (int j = tid; j < F; j += 256) s = fmaf(H[row * F + j], v[j], s);
    sdata[tid] = s;
    __syncthreads();
    for (int off = 128; off > 0; off >>= 1) {
        if (tid < off) sdata[tid] += sdata[tid + off];
        __syncthreads();
    }
    if (tid == 0) y[row] = sdata[0];
}

__global__ void normalize_kernel(const float* __restrict__ y, float* __restrict__ v,
                                 float* __restrict__ scal) {
    __shared__ float sdata[256];
    __shared__ float lam;
    int tid = threadIdx.x;
    float s = 0.f;
    for (int i = tid; i < F; i += 256) {
        float t = y[i];
        s = fmaf(t, t, s);
    }
    sdata[tid] = s;
    __syncthreads();
    for (int off = 128; off > 0; off >>= 1) {
        if (tid < off) sdata[tid] += sdata[tid + off];
        __syncthreads();
    }
    if (tid == 0) {
        lam = sqrtf(sdata[0]);
        scal[2] = lam;
        scal[3] = 1.0f / (1.02f * lam);
    }
    __syncthreads();
    float il = 1.0f / lam;
    for (int i = tid; i < F; i += 256) v[i] = y[i] * il;
}

// ---------------- init X0 = c*I (+ bf16 split) ----------------
__global__ void initX_kernel(float* __restrict__ Xc, ushort_t* __restrict__ Xchi,
                             ushort_t* __restrict__ Xclo, const float* __restrict__ scal) {
    int idx = blockIdx.x * 256 + threadIdx.x;
    int i = idx >> 10, j = idx & (F - 1);
    float val = (i == j) ? scal[3] : 0.0f;
    Xc[idx] = val;
    ushort_t h = f2bf(val);
    Xchi[idx] = h;
    Xclo[idx] = f2bf(val - bf2f(h));
}

// ---------------- finalize ----------------
__global__ void finalize_kernel(const float* __restrict__ A, float* __restrict__ out) {
    int idx = blockIdx.x * 256 + threadIdx.x;
    if (idx < F * F) out[idx] = A[idx];
    else if (idx < F * F + F) out[idx] = (float)(idx - F * F);
}

// ======================= fp32 fallback path (round-1 kernels) =======================
__global__ __launch_bounds__(256) void syrk_kernel(const float* __restrict__ X,
                                                   float* __restrict__ H,
                                                   const float* __restrict__ scal) {
    __shared__ float LA[16][64];
    __shared__ float LB[16][64];
    int tx = threadIdx.x, ty = threadIdx.y;
    int t = ty * 16 + tx;
    int i0 = blockIdx.y * 64, j0 = blockIdx.x * 64;
    int lk = t >> 4;
    int lc = (t & 15) << 2;
    float acc[4][4] = {};
    for (int k0 = 0; k0 < NROWS; k0 += 16) {
        int r = (k0 + lk) * F;
        float4 a4 = *(const float4*)&X[r + i0 + lc];
        float4 b4 = *(const float4*)&X[r + j0 + lc];
        __syncthreads();
        *(float4*)&LA[lk][lc] = a4;
        *(float4*)&LB[lk][lc] = b4;
        __syncthreads();
#pragma unroll
        for (int kk = 0; kk < 16; ++kk) {
            float4 a = *(const float4*)&LA[kk][ty << 2];
            float4 b = *(const float4*)&LB[kk][tx << 2];
            float av[4] = {a.x, a.y, a.z, a.w};
            float bv[4] = {b.x, b.y, b.z, b.w};
#pragma unroll
            for (int rr = 0; rr < 4; ++rr)
#pragma unroll
                for (int cc = 0; cc < 4; ++cc)
                    acc[rr][cc] = fmaf(av[rr], bv[cc], acc[rr][cc]);
        }
    }
    float damp = scal[1];
#pragma unroll
    for (int rr = 0; rr < 4; ++rr) {
        int i = i0 + (ty << 2) + rr;
#pragma unroll
        for (int cc = 0; cc < 4; ++cc) {
            int j = j0 + (tx << 2) + cc;
            float v = acc[rr][cc];
            if (i == j) v += damp;
            H[i * F + j] = v;
        }
    }
}

__global__ void init_X_kernel(float* __restrict__ A, const float* __restrict__ scal) {
    int idx = blockIdx.x * 256 + threadIdx.x;
    int i = idx >> 10, j = idx & (F - 1);
    A[idx] = (i == j) ? scal[3] : 0.0f;
}

__global__ __launch_bounds__(256) void gemm_nn_kernel(const float* __restrict__ A,
                                                      const float* __restrict__ Bm,
                                                      float* __restrict__ C,
                                                      const float* __restrict__ D,
                                                      int mode) {
    __shared__ float LA[16][64];
    __shared__ float LB[16][64];
    int tx = threadIdx.x, ty = threadIdx.y;
    int t = ty * 16 + tx;
    int i0 = blockIdx.y * 64, j0 = blockIdx.x * 64;
    int aii = t >> 2;
    int akq = (t & 3) << 2;
    int bkk = t >> 4;
    int bjq = (t & 15) << 2;
    float acc[4][4] = {};
    for (int k0 = 0; k0 < F; k0 += 16) {
        float4 a4 = *(const float4*)&A[(i0 + aii) * F + k0 + akq];
        float4 b4 = *(const float4*)&Bm[(k0 + bkk) * F + j0 + bjq];
        __syncthreads();
        LA[akq + 0][aii] = a4.x;
        LA[akq + 1][aii] = a4.y;
        LA[akq + 2][aii] = a4.z;
        LA[akq + 3][aii] = a4.w;
        *(float4*)&LB[bkk][bjq] = b4;
        __syncthreads();
#pragma unroll
        for (int kk = 0; kk < 16; ++kk) {
            float4 a = *(const float4*)&LA[kk][ty << 2];
            float4 b = *(const float4*)&LB[kk][tx << 2];
            float av[4] = {a.x, a.y, a.z, a.w};
            float bv[4] = {b.x, b.y, b.z, b.w};
#pragma unroll
            for (int rr = 0; rr < 4; ++rr)
#pragma unroll
                for (int cc = 0; cc < 4; ++cc)
                    acc[rr][cc] = fmaf(av[rr], bv[cc], acc[rr][cc]);
        }
    }
#pragma unroll
    for (int rr = 0; rr < 4; ++rr) {
        int i = i0 + (ty << 2) + rr;
#pragma unroll
        for (int cc = 0; cc < 4; ++cc) {
            int j = j0 + (tx << 2) + cc;
            float v = acc[rr][cc];
            if (mode == 1) v = 2.0f * D[i * F + j] - v;
            C[i * F + j] = v;
        }
    }
}

// ======================= launch =======================
extern "C" void kernel_launch(void* const* d_in, const int* in_sizes, int n_in,
                              void* d_out, int out_size, void* d_ws, size_t ws_size,
                              hipStream_t stream) {
    const float* x = (const float*)d_in[0];
    float* out = (float*)d_out;

    // ---- new-path workspace layout ----
    char* base = (char*)d_ws;
    size_t off = 0;
    auto alloc = [&](size_t bytes) -> char* {
        char* p = base + off;
        off += bytes;
        off = (off + 255) & ~(size_t)255;
        return p;
    };
    float*    scal  = (float*)alloc(64 * 4);
    float*    part  = (float*)alloc(2048 * 4);
    ushort_t* XThi  = (ushort_t*)alloc((size_t)NELEM * 2);
    ushort_t* XTlo  = (ushort_t*)alloc((size_t)NELEM * 2);
    float*    H     = (float*)alloc((size_t)F * F * 4);
    ushort_t* Hhi   = (ushort_t*)alloc((size_t)F * F * 2);
    ushort_t* Hlo   = (ushort_t*)alloc((size_t)F * F * 2);
    float*    X0f   = (float*)alloc((size_t)F * F * 4);
    float*    X1f   = (float*)alloc((size_t)F * F * 4);
    ushort_t* X0hi  = (ushort_t*)alloc((size_t)F * F * 2);
    ushort_t* X0lo  = (ushort_t*)alloc((size_t)F * F * 2);
    ushort_t* X1hi  = (ushort_t*)alloc((size_t)F * F * 2);
    ushort_t* X1lo  = (ushort_t*)alloc((size_t)F * F * 2);
    ushort_t* Shi   = (ushort_t*)alloc((size_t)F * F * 2);
    ushort_t* Slo   = (ushort_t*)alloc((size_t)F * F * 2);
    float*    P     = (float*)alloc((size_t)4 * F * F * 4);
    float*    v     = (float*)alloc(F * 4);
    float*    y     = (float*)alloc(F * 4);
    size_t need = off;

    if (ws_size >= need) {
        // ======== MFMA path ========
        sumsq_partial_kernel<<<2048, 256, 0, stream>>>(x, part);
        finish_damp_kernel<<<1, 256, 0, stream>>>(part, scal);

        tconv_kernel<<<dim3(16, 128), 256, 0, stream>>>(x, XThi, XTlo);

        // H = X^T X + damp*I : A' rows = XT rows(i), B' rows = XT rows(j), K=8192
        mfma_gemm_kernel<<<dim3(8, 8, 4), 256, 0, stream>>>(XThi, XTlo, XThi, XTlo,
                                                            8192, 8192, 2048, P, 3);
        reduceH_kernel<<<1024, 256, 0, stream>>>(P, H, Hhi, Hlo, scal);

        init_v_kernel<<<4, 256, 0, stream>>>(v);
        for (int it = 0; it < 8; ++it) {
            matvec_kernel<<<F, 256, 0, stream>>>(H, v, y);
            normalize_kernel<<<1, 256, 0, stream>>>(y, v, scal);
        }

        initX_kernel<<<(F * F) / 256, 256, 0, stream>>>(X0f, X0hi, X0lo, scal);

        float*    Xcf = X0f;  float*    Xnf = X1f;
        ushort_t* xch = X0hi; ushort_t* xcl = X0lo;
        ushort_t* xnh = X1hi; ushort_t* xnl = X1lo;
        for (int it = 0; it < 8; ++it) {
            int terms = (it < 5) ? 1 : 3;
            // S = Xc * H   (B-operand rows = H rows; H symmetric)
            mfma_gemm_kernel<<<dim3(8, 8, 4), 256, 0, stream>>>(xch, xcl, Hhi, Hlo,
                                                                F, F, 256, P, terms);
            reduceS_kernel<<<1024, 256, 0, stream>>>(P, Shi, Slo);
            // Xn = 2*Xc - S * Xc  (B-operand rows = Xc rows; Xc symmetric)
            mfma_gemm_kernel<<<dim3(8, 8, 4), 256, 0, stream>>>(Shi, Slo, xch, xcl,
                                                                F, F, 256, P, terms);
            reduceX_kernel<<<1024, 256, 0, stream>>>(P, Xcf, Xnf, xnh, xnl);
            // swap
            float* tf = Xcf; Xcf = Xnf; Xnf = tf;
            ushort_t* th = xch; xch = xnh; xnh = th;
            ushort_t* tl = xcl; xcl = xnl; xnl = tl;
        }

        finalize_kernel<<<(F * F + F + 255) / 256, 256, 0, stream>>>(Xcf, out);
    } else {
        // ======== fp32 fallback (round-1 path) ========
        float* ws = (float*)d_ws;
        float* fscal    = ws;
        float* fpartial = ws + 64;
        float* fH  = ws + 4096;
        float* fA  = fH + F * F;
        float* fB  = fA + F * F;
        float* fv  = fB + F * F;
        float* fy  = fv + F;
        float* R = out;

        sumsq_partial_kernel<<<2048, 256, 0, stream>>>(x, fpartial);
        finish_damp_kernel<<<1, 256, 0, stream>>>(fpartial, fscal);

        dim3 grid16(16, 16), blk16(16, 16);
        syrk_kernel<<<grid16, blk16, 0, stream>>>(x, fH, fscal);

        init_v_kernel<<<4, 256, 0, stream>>>(fv);
        for (int it = 0; it < 12; ++it) {
            matvec_kernel<<<F, 256, 0, stream>>>(fH, fv, fy);
            normalize_kernel<<<1, 256, 0, stream>>>(fy, fv, fscal);
        }

        init_X_kernel<<<(F * F) / 256, 256, 0, stream>>>(fA, fscal);
        float* Xc = fA;
        float* Xn = fB;
        for (int it = 0; it < 8; ++it) {
            gemm_nn_kernel<<<grid16, blk16, 0, stream>>>(fH, Xc, R, nullptr, 0);
            gemm_nn_kernel<<<grid16, blk16, 0, stream>>>(Xc, R, Xn, Xc, 1);
            float* tmp = Xc; Xc = Xn; Xn = tmp;
        }

        finalize_kernel<<<(F * F + F + 255) / 256, 256, 0, stream>>>(Xc, out);
    }
}

// Round 3
// 250.194 us; speedup vs baseline: 6.1229x; 1.9119x over previous
//
#include <hip/hip_runtime.h>
#include <math.h>

#define F 1024
#define NROWS 8192
#define NELEM (NROWS * F)

typedef unsigned short ushort_t;
typedef short bf16x8 __attribute__((ext_vector_type(8)));
typedef float f32x4 __attribute__((ext_vector_type(4)));
typedef unsigned short ushort8 __attribute__((ext_vector_type(8)));

__device__ __forceinline__ ushort_t f2bf(float f) {
  unsigned u = __float_as_uint(f);
  unsigned r = (u + 0x7fffu + ((u >> 16) & 1u)) >> 16;
  return (ushort_t)r;
}
__device__ __forceinline__ float bf2f(ushort_t b) {
  return __uint_as_float(((unsigned)b) << 16);
}

typedef const __attribute__((address_space(1))) unsigned int* gas_ptr;
typedef __attribute__((address_space(3))) unsigned int* las_ptr;
__device__ __forceinline__ void gload16(const void* g, const void* l) {
  __builtin_amdgcn_global_load_lds((gas_ptr)(unsigned long long)g,
                                   (las_ptr)(unsigned int)(unsigned long long)l,
                                   16, 0, 0);
}

// ---------------- tconv + fused sumsq: X (8192x1024 f32) -> XT hi/lo bf16; partial sum x^2 ----------------
__global__ __launch_bounds__(256) void tconv_kernel(const float* __restrict__ x,
                                                    ushort_t* __restrict__ xthi,
                                                    ushort_t* __restrict__ xtlo,
                                                    float* __restrict__ partial) {
    __shared__ ushort_t th[64][68];
    __shared__ ushort_t tl[64][68];
    __shared__ float sdata[256];
    int c0 = blockIdx.x * 64;   // col of X (0..1023)
    int r0 = blockIdx.y * 64;   // row of X (0..8191)
    int tid = threadIdx.x;
    float ss = 0.f;
#pragma unroll
    for (int i = 0; i < 4; ++i) {
        int q = tid + 256 * i;
        int r = q >> 4;            // 0..63
        int cq = (q & 15) << 2;    // 0..60
        float4 vx = *(const float4*)&x[(size_t)(r0 + r) * 1024 + c0 + cq];
        float vv[4] = {vx.x, vx.y, vx.z, vx.w};
#pragma unroll
        for (int j = 0; j < 4; ++j) {
            ss = fmaf(vv[j], vv[j], ss);
            ushort_t h = f2bf(vv[j]);
            ushort_t l = f2bf(vv[j] - bf2f(h));
            th[r][cq + j] = h;
            tl[r][cq + j] = l;
        }
    }
    sdata[tid] = ss;
    __syncthreads();
    for (int off = 128; off > 0; off >>= 1) {
        if (tid < off) sdata[tid] += sdata[tid + off];
        __syncthreads();
    }
    if (tid == 0) partial[blockIdx.y * 16 + blockIdx.x] = sdata[0];
#pragma unroll
    for (int i = 0; i < 2; ++i) {
        int q = tid + 256 * i;
        int c = q >> 3;            // 0..63
        int rq = (q & 7) << 3;     // 0..56
        ushort8 oh, ol;
#pragma unroll
        for (int j = 0; j < 8; ++j) {
            oh[j] = th[rq + j][c];
            ol[j] = tl[rq + j][c];
        }
        *(ushort8*)&xthi[(size_t)(c0 + c) * 8192 + r0 + rq] = oh;
        *(ushort8*)&xtlo[(size_t)(c0 + c) * 8192 + r0 + rq] = ol;
    }
}

__global__ void finish_damp_kernel(const float* __restrict__ partial, float* __restrict__ scal) {
    __shared__ float sdata[256];
    int tid = threadIdx.x;
    float s = 0.f;
    for (int i = tid; i < 2048; i += 256) s += partial[i];
    sdata[tid] = s;
    __syncthreads();
    for (int off = 128; off > 0; off >>= 1) {
        if (tid < off) sdata[tid] += sdata[tid + off];
        __syncthreads();
    }
    if (tid == 0) {
        float mean = sdata[0] / (float)NELEM;
        scal[1] = 0.01f * mean;   // damp
    }
}

// ---------------- SYRK: triangle tiles, split-K z=8, z->XCD swizzle, dbuf ----------------
// grid(288): z = id&7 (XCD), t = id>>3 (0..35 triangle tile). kchunk=1024.
// P layout: P[(t*8+z)*16384 + r*128 + c]
__device__ __forceinline__ void stage128(const ushort_t* __restrict__ gp, int row0, int kk,
                                         ushort_t* sbase, int w, int lane) {
#pragma unroll
    for (int half = 0; half < 2; ++half) {
        int s = half * 256 + (w << 6) + lane;
        int r = s >> 2, pos = s & 3;
        int kc = (pos ^ ((r >> 1) & 3)) << 3;
        gload16(gp + (size_t)(row0 + r) * 8192 + kk + kc,
                sbase + (size_t)((half << 8) + (w << 6)) * 8);
    }
}

__global__ __launch_bounds__(256, 2) void syrk_mfma_kernel(
    const ushort_t* __restrict__ XThi, const ushort_t* __restrict__ XTlo,
    float* __restrict__ P)
{
    __shared__ ushort_t smem[2][16384];   // per buf: Ahi@0 Alo@4096 Bhi@8192 Blo@12288
    int id = blockIdx.x;
    int z = id & 7, t = id >> 3;
    int bi = 0;
    while ((bi + 1) * (bi + 2) / 2 <= t) ++bi;
    int bj = t - bi * (bi + 1) / 2;
    int arow0 = bi * 128, brow0 = bj * 128;
    int k0 = z * 1024;

    int tid = threadIdx.x, lane = tid & 63, w = tid >> 6;
    int wm = w >> 1, wn = w & 1;
    int lr = lane & 15, cg = lane >> 4;

    f32x4 zero4 = {0.f, 0.f, 0.f, 0.f};
    f32x4 acc[4][4];
#pragma unroll
    for (int a = 0; a < 4; ++a)
#pragma unroll
        for (int b = 0; b < 4; ++b) acc[a][b] = zero4;

    // prologue: stage tile 0 into buf 0
    {
        ushort_t* sb = smem[0];
        stage128(XThi, arow0, k0, sb + 0, w, lane);
        stage128(XTlo, arow0, k0, sb + 4096, w, lane);
        stage128(XThi, brow0, k0, sb + 8192, w, lane);
        stage128(XTlo, brow0, k0, sb + 12288, w, lane);
    }

#define SYRK_COMPUTE(BUF)                                                          \
    {                                                                              \
        ushort_t* sb = smem[BUF];                                                  \
        bf16x8 ah[4], bh[4], al[4], bl[4];                                         \
        _Pragma("unroll")                                                          \
        for (int fx = 0; fx < 4; ++fx) {                                           \
            int ar = (wm << 6) + (fx << 4) + lr;                                   \
            int br = (wn << 6) + (fx << 4) + lr;                                   \
            int ao = ar * 32 + ((cg ^ ((lr >> 1) & 3)) << 3);                      \
            int bo = br * 32 + ((cg ^ ((lr >> 1) & 3)) << 3);                      \
            ah[fx] = *(const bf16x8*)&sb[0 + ao];                                  \
            al[fx] = *(const bf16x8*)&sb[4096 + ao];                               \
            bh[fx] = *(const bf16x8*)&sb[8192 + bo];                               \
            bl[fx] = *(const bf16x8*)&sb[12288 + bo];                              \
        }                                                                          \
        _Pragma("unroll")                                                          \
        for (int fm = 0; fm < 4; ++fm)                                             \
            _Pragma("unroll")                                                      \
            for (int fn = 0; fn < 4; ++fn) {                                       \
                acc[fm][fn] = __builtin_amdgcn_mfma_f32_16x16x32_bf16(             \
                    ah[fm], bh[fn], acc[fm][fn], 0, 0, 0);                         \
                acc[fm][fn] = __builtin_amdgcn_mfma_f32_16x16x32_bf16(             \
                    ah[fm], bl[fn], acc[fm][fn], 0, 0, 0);                         \
                acc[fm][fn] = __builtin_amdgcn_mfma_f32_16x16x32_bf16(             \
                    al[fm], bh[fn], acc[fm][fn], 0, 0, 0);                         \
            }                                                                      \
    }

    for (int kt = 0; kt < 31; ++kt) {
        int buf = kt & 1;
        {   // stage next tile into other buffer
            ushort_t* sb = smem[buf ^ 1];
            int kk = k0 + ((kt + 1) << 5);
            stage128(XThi, arow0, kk, sb + 0, w, lane);
            stage128(XTlo, arow0, kk, sb + 4096, w, lane);
            stage128(XThi, brow0, kk, sb + 8192, w, lane);
            stage128(XTlo, brow0, kk, sb + 12288, w, lane);
        }
        asm volatile("s_waitcnt vmcnt(8)" ::: "memory");
        __builtin_amdgcn_s_barrier();
        __builtin_amdgcn_sched_barrier(0);
        if (buf == 0) SYRK_COMPUTE(0) else SYRK_COMPUTE(1)
        __builtin_amdgcn_sched_barrier(0);
        __builtin_amdgcn_s_barrier();
    }
    asm volatile("s_waitcnt vmcnt(0)" ::: "memory");
    __builtin_amdgcn_s_barrier();
    __builtin_amdgcn_sched_barrier(0);
    SYRK_COMPUTE(1)   // kt=31 -> buf 1

    float* Pt = P + ((size_t)(t * 8 + z) << 14);
#pragma unroll
    for (int fm = 0; fm < 4; ++fm)
#pragma unroll
        for (int fn = 0; fn < 4; ++fn)
#pragma unroll
            for (int rr = 0; rr < 4; ++rr) {
                int row = (wm << 6) + fm * 16 + cg * 4 + rr;
                int col = (wn << 6) + fn * 16 + lr;
                Pt[row * 128 + col] = acc[fm][fn][rr];
            }
}

// ---------------- reduceH: sum 8 z-slices, +damp, split to bf16 hi/lo, mirror ----------------
__global__ void reduceH_kernel(const float* __restrict__ P,
                               ushort_t* __restrict__ Hhi, ushort_t* __restrict__ Hlo,
                               const float* __restrict__ scal) {
    int b = blockIdx.x;
    int tile = b >> 6;
    int li = ((b & 63) << 8) + threadIdx.x;
    int bi = 0;
    while ((bi + 1) * (bi + 2) / 2 <= tile) ++bi;
    int bj = tile - bi * (bi + 1) / 2;
    const float* Pt = P + ((size_t)tile << 17);
    float s = 0.f;
#pragma unroll
    for (int z = 0; z < 8; ++z) s += Pt[((size_t)z << 14) + li];
    int r = li >> 7, c = li & 127;
    int gi = bi * 128 + r, gj = bj * 128 + c;
    if (gi == gj) s += scal[1];
    ushort_t h = f2bf(s), l = f2bf(s - bf2f(h));
    Hhi[gi * F + gj] = h;
    Hlo[gi * F + gj] = l;
    if (bi != bj) {
        Hhi[gj * F + gi] = h;
        Hlo[gj * F + gi] = l;
    }
}

// ---------------- power iteration (on Hhi, bf16) ----------------
__global__ void init_v_kernel(float* __restrict__ v) {
    int i = blockIdx.x * 256 + threadIdx.x;
    if (i < F) v[i] = 1.0f;
}

__global__ void matvec_bf16_kernel(const ushort_t* __restrict__ Hhi, const float* __restrict__ v,
                                   float* __restrict__ y) {
    __shared__ float sdata[256];
    int row = blockIdx.x, tid = threadIdx.x;
    float s = 0.f;
    for (int j = tid; j < F; j += 256) s = fmaf(bf2f(Hhi[row * F + j]), v[j], s);
    sdata[tid] = s;
    __syncthreads();
    for (int off = 128; off > 0; off >>= 1) {
        if (tid < off) sdata[tid] += sdata[tid + off];
        __syncthreads();
    }
    if (tid == 0) y[row] = sdata[0];
}

__global__ void normalize_kernel(const float* __restrict__ y, float* __restrict__ v,
                                 float* __restrict__ scal) {
    __shared__ float sdata[256];
    __shared__ float lam;
    int tid = threadIdx.x;
    float s = 0.f;
    for (int i = tid; i < F; i += 256) {
        float t = y[i];
        s = fmaf(t, t, s);
    }
    sdata[tid] = s;
    __syncthreads();
    for (int off = 128; off > 0; off >>= 1) {
        if (tid < off) sdata[tid] += sdata[tid + off];
        __syncthreads();
    }
    if (tid == 0) {
        lam = sqrtf(sdata[0]);
        scal[2] = lam;
        scal[3] = 1.0f / (1.05f * lam);   // Newton-Schulz scale c (1.05 safety)
    }
    __syncthreads();
    float il = 1.0f / lam;
    for (int i = tid; i < F; i += 256) v[i] = y[i] * il;
}

// ---------------- init X0 = c*I (bf16 split only) ----------------
__global__ void initX_kernel(ushort_t* __restrict__ Xchi, ushort_t* __restrict__ Xclo,
                             const float* __restrict__ scal) {
    int idx = blockIdx.x * 256 + threadIdx.x;
    int i = idx >> 10, j = idx & (F - 1);
    float val = (i == j) ? scal[3] : 0.0f;
    ushort_t h = f2bf(val);
    Xchi[idx] = h;
    Xclo[idx] = f2bf(val - bf2f(h));
}

// ---------------- NS GEMM: 64x64 tile, K=1024, dbuf, fused epilogue ----------------
// C[m][n] = sum_k A[m][k] * B[n][k]  (B symmetric => equals A@B)
// MODE 0: write split(acc) to Ohi/Olo          (S = Xc*H)
// MODE 1: val = 2*(Xchi+Xclo) - acc, write split to Ohi/Olo   (Xn mid-iter)
// MODE 2: val = 2*(Xchi+Xclo) - acc, write fp32 to Of         (final -> d_out)
__device__ __forceinline__ void stage64(const ushort_t* __restrict__ gp, int row0, int kk,
                                        ushort_t* sbase, int tid) {
    int r = tid >> 2, pos = tid & 3;
    int kc = (pos ^ ((r >> 1) & 3)) << 3;
    gload16(gp + (size_t)(row0 + r) * 1024 + kk + kc, sbase + (size_t)(tid >> 6 << 9));
}

template <int TERMS, int MODE>
__global__ __launch_bounds__(256, 2) void ns_gemm_kernel(
    const ushort_t* __restrict__ Ahi, const ushort_t* __restrict__ Alo,
    const ushort_t* __restrict__ Bhi, const ushort_t* __restrict__ Blo,
    const ushort_t* __restrict__ Xchi, const ushort_t* __restrict__ Xclo,
    ushort_t* __restrict__ Ohi, ushort_t* __restrict__ Olo,
    float* __restrict__ Of)
{
    __shared__ ushort_t smem[2][8192];   // per buf: Ahi@0 Alo@2048 Bhi@4096 Blo@6144
    int tid = threadIdx.x, lane = tid & 63, w = tid >> 6;
    int wm = w >> 1, wn = w & 1;
    int row0 = blockIdx.y * 64, col0 = blockIdx.x * 64;
    int lr = lane & 15, cg = lane >> 4;

    f32x4 zero4 = {0.f, 0.f, 0.f, 0.f};
    f32x4 acc[2][2];
#pragma unroll
    for (int a = 0; a < 2; ++a)
#pragma unroll
        for (int b = 0; b < 2; ++b) acc[a][b] = zero4;

    {   // prologue stage tile 0
        ushort_t* sb = smem[0];
        stage64(Ahi, row0, 0, sb + 0, tid);
        stage64(Bhi, col0, 0, sb + 4096, tid);
        if constexpr (TERMS == 3) {
            stage64(Alo, row0, 0, sb + 2048, tid);
            stage64(Blo, col0, 0, sb + 6144, tid);
        }
    }

#define NS_COMPUTE(BUF)                                                            \
    {                                                                              \
        ushort_t* sb = smem[BUF];                                                  \
        bf16x8 ah[2], bh[2], al[2], bl[2];                                         \
        _Pragma("unroll")                                                          \
        for (int fx = 0; fx < 2; ++fx) {                                           \
            int xo = (cg ^ ((lr >> 1) & 3)) << 3;                                  \
            int ao = ((wm << 5) + (fx << 4) + lr) * 32 + xo;                       \
            int bo = ((wn << 5) + (fx << 4) + lr) * 32 + xo;                       \
            ah[fx] = *(const bf16x8*)&sb[0 + ao];                                  \
            bh[fx] = *(const bf16x8*)&sb[4096 + bo];                               \
            if constexpr (TERMS == 3) {                                            \
                al[fx] = *(const bf16x8*)&sb[2048 + ao];                           \
                bl[fx] = *(const bf16x8*)&sb[6144 + bo];                           \
            }                                                                      \
        }                                                                          \
        _Pragma("unroll")                                                          \
        for (int fm = 0; fm < 2; ++fm)                                             \
            _Pragma("unroll")                                                      \
            for (int fn = 0; fn < 2; ++fn) {                                       \
                acc[fm][fn] = __builtin_amdgcn_mfma_f32_16x16x32_bf16(             \
                    ah[fm], bh[fn], acc[fm][fn], 0, 0, 0);                         \
                if constexpr (TERMS == 3) {                                        \
                    acc[fm][fn] = __builtin_amdgcn_mfma_f32_16x16x32_bf16(         \
                        ah[fm], bl[fn], acc[fm][fn], 0, 0, 0);                     \
                    acc[fm][fn] = __builtin_amdgcn_mfma_f32_16x16x32_bf16(         \
                        al[fm], bh[fn], acc[fm][fn], 0, 0, 0);                     \
                }                                                                  \
            }                                                                      \
    }

    for (int kt = 0; kt < 31; ++kt) {
        int buf = kt & 1;
        {
            ushort_t* sb = smem[buf ^ 1];
            int kk = (kt + 1) << 5;
            stage64(Ahi, row0, kk, sb + 0, tid);
            stage64(Bhi, col0, kk, sb + 4096, tid);
            if constexpr (TERMS == 3) {
                stage64(Alo, row0, kk, sb + 2048, tid);
                stage64(Blo, col0, kk, sb + 6144, tid);
            }
        }
        if constexpr (TERMS == 3)
            asm volatile("s_waitcnt vmcnt(4)" ::: "memory");
        else
            asm volatile("s_waitcnt vmcnt(2)" ::: "memory");
        __builtin_amdgcn_s_barrier();
        __builtin_amdgcn_sched_barrier(0);
        if (buf == 0) NS_COMPUTE(0) else NS_COMPUTE(1)
        __builtin_amdgcn_sched_barrier(0);
        __builtin_amdgcn_s_barrier();
    }
    asm volatile("s_waitcnt vmcnt(0)" ::: "memory");
    __builtin_amdgcn_s_barrier();
    __builtin_amdgcn_sched_barrier(0);
    NS_COMPUTE(1)   // kt=31

#pragma unroll
    for (int fm = 0; fm < 2; ++fm)
#pragma unroll
        for (int fn = 0; fn < 2; ++fn)
#pragma unroll
            for (int rr = 0; rr < 4; ++rr) {
                int r = row0 + (wm << 5) + fm * 16 + cg * 4 + rr;
                int c = col0 + (wn << 5) + fn * 16 + lr;
                size_t idx = (size_t)r * F + c;
                float val = acc[fm][fn][rr];
                if constexpr (MODE == 0) {
                    ushort_t h = f2bf(val);
                    Ohi[idx] = h;
                    Olo[idx] = f2bf(val - bf2f(h));
                } else {
                    float xc = bf2f(Xchi[idx]) + bf2f(Xclo[idx]);
                    val = 2.0f * xc - val;
                    if constexpr (MODE == 1) {
                        ushort_t h = f2bf(val);
                        Ohi[idx] = h;
                        Olo[idx] = f2bf(val - bf2f(h));
                    } else {
                        Of[idx] = val;
                    }
                }
            }
}

// ---------------- perm tail ----------------
__global__ void perm_kernel(float* __restrict__ out) {
    int i = blockIdx.x * 256 + threadIdx.x;
    if (i < F) out[(size_t)F * F + i] = (float)i;
}

// ======================= fp32 fallback path =======================
__global__ void sumsq_partial_kernel(const float* __restrict__ x, float* __restrict__ partial) {
    __shared__ float sdata[256];
    int tid = threadIdx.x;
    int base = blockIdx.x * 4096;
    float s = 0.f;
    for (int i = tid; i < 4096; i += 256) {
        float v = x[base + i];
        s = fmaf(v, v, s);
    }
    sdata[tid] = s;
    __syncthreads();
    for (int off = 128; off > 0; off >>= 1) {
        if (tid < off) sdata[tid] += sdata[tid + off];
        __syncthreads();
    }
    if (tid == 0) partial[blockIdx.x] = sdata[0];
}

__global__ void matvec_kernel(const float* __restrict__ H, const float* __restrict__ v,
                              float* __restrict__ y) {
    __shared__ float sdata[256];
    int row = blockIdx.x, tid = threadIdx.x;
    float s = 0.f;
    for (int j = tid; j < F; j += 256) s = fmaf(H[row * F + j], v[j], s);
    sdata[tid] = s;
    __syncthreads();
    for (int off = 128; off > 0; off >>= 1) {
        if (tid < off) sdata[tid] += sdata[tid + off];
        __syncthreads();
    }
    if (tid == 0) y[row] = sdata[0];
}

__global__ __launch_bounds__(256) void syrk_kernel(const float* __restrict__ X,
                                                   float* __restrict__ H,
                                                   const float* __restrict__ scal) {
    __shared__ float LA[16][64];
    __shared__ float LB[16][64];
    int tx = threadIdx.x, ty = threadIdx.y;
    int t = ty * 16 + tx;
    int i0 = blockIdx.y * 64, j0 = blockIdx.x * 64;
    int lk = t >> 4;
    int lc = (t & 15) << 2;
    float acc[4][4] = {};
    for (int k0 = 0; k0 < NROWS; k0 += 16) {
        int r = (k0 + lk) * F;
        float4 a4 = *(const float4*)&X[r + i0 + lc];
        float4 b4 = *(const float4*)&X[r + j0 + lc];
        __syncthreads();
        *(float4*)&LA[lk][lc] = a4;
        *(float4*)&LB[lk][lc] = b4;
        __syncthreads();
#pragma unroll
        for (int kk = 0; kk < 16; ++kk) {
            float4 a = *(const float4*)&LA[kk][ty << 2];
            float4 b = *(const float4*)&LB[kk][tx << 2];
            float av[4] = {a.x, a.y, a.z, a.w};
            float bv[4] = {b.x, b.y, b.z, b.w};
#pragma unroll
            for (int rr = 0; rr < 4; ++rr)
#pragma unroll
                for (int cc = 0; cc < 4; ++cc)
                    acc[rr][cc] = fmaf(av[rr], bv[cc], acc[rr][cc]);
        }
    }
    float damp = scal[1];
#pragma unroll
    for (int rr = 0; rr < 4; ++rr) {
        int i = i0 + (ty << 2) + rr;
#pragma unroll
        for (int cc = 0; cc < 4; ++cc) {
            int j = j0 + (tx << 2) + cc;
            float v = acc[rr][cc];
            if (i == j) v += damp;
            H[i * F + j] = v;
        }
    }
}

__global__ void init_X_kernel(float* __restrict__ A, const float* __restrict__ scal) {
    int idx = blockIdx.x * 256 + threadIdx.x;
    int i = idx >> 10, j = idx & (F - 1);
    A[idx] = (i == j) ? scal[3] : 0.0f;
}

__global__ __launch_bounds__(256) void gemm_nn_kernel(const float* __restrict__ A,
                                                      const float* __restrict__ Bm,
                                                      float* __restrict__ C,
                                                      const float* __restrict__ D,
                                                      int mode) {
    __shared__ float LA[16][64];
    __shared__ float LB[16][64];
    int tx = threadIdx.x, ty = threadIdx.y;
    int t = ty * 16 + tx;
    int i0 = blockIdx.y * 64, j0 = blockIdx.x * 64;
    int aii = t >> 2;
    int akq = (t & 3) << 2;
    int bkk = t >> 4;
    int bjq = (t & 15) << 2;
    float acc[4][4] = {};
    for (int k0 = 0; k0 < F; k0 += 16) {
        float4 a4 = *(const float4*)&A[(i0 + aii) * F + k0 + akq];
        float4 b4 = *(const float4*)&Bm[(k0 + bkk) * F + j0 + bjq];
        __syncthreads();
        LA[akq + 0][aii] = a4.x;
        LA[akq + 1][aii] = a4.y;
        LA[akq + 2][aii] = a4.z;
        LA[akq + 3][aii] = a4.w;
        *(float4*)&LB[bkk][bjq] = b4;
        __syncthreads();
#pragma unroll
        for (int kk = 0; kk < 16; ++kk) {
            float4 a = *(const float4*)&LA[kk][ty << 2];
            float4 b = *(const float4*)&LB[kk][tx << 2];
            float av[4] = {a.x, a.y, a.z, a.w};
            float bv[4] = {b.x, b.y, b.z, b.w};
#pragma unroll
            for (int rr = 0; rr < 4; ++rr)
#pragma unroll
                for (int cc = 0; cc < 4; ++cc)
                    acc[rr][cc] = fmaf(av[rr], bv[cc], acc[rr][cc]);
        }
    }
#pragma unroll
    for (int rr = 0; rr < 4; ++rr) {
        int i = i0 + (ty << 2) + rr;
#pragma unroll
        for (int cc = 0; cc < 4; ++cc) {
            int j = j0 + (tx << 2) + cc;
            float v = acc[rr][cc];
            if (mode == 1) v = 2.0f * D[i * F + j] - v;
            C[i * F + j] = v;
        }
    }
}

__global__ void finalize_kernel(const float* __restrict__ A, float* __restrict__ out) {
    int idx = blockIdx.x * 256 + threadIdx.x;
    if (idx < F * F) out[idx] = A[idx];
    else if (idx < F * F + F) out[idx] = (float)(idx - F * F);
}

// ======================= launch =======================
extern "C" void kernel_launch(void* const* d_in, const int* in_sizes, int n_in,
                              void* d_out, int out_size, void* d_ws, size_t ws_size,
                              hipStream_t stream) {
    const float* x = (const float*)d_in[0];
    float* out = (float*)d_out;

    char* base = (char*)d_ws;
    size_t off = 0;
    auto alloc = [&](size_t bytes) -> char* {
        char* p = base + off;
        off += bytes;
        off = (off + 255) & ~(size_t)255;
        return p;
    };
    float*    scal = (float*)alloc(64 * 4);
    float*    part = (float*)alloc(2048 * 4);
    ushort_t* XThi = (ushort_t*)alloc((size_t)NELEM * 2);
    ushort_t* XTlo = (ushort_t*)alloc((size_t)NELEM * 2);
    ushort_t* Hhi  = (ushort_t*)alloc((size_t)F * F * 2);
    ushort_t* Hlo  = (ushort_t*)alloc((size_t)F * F * 2);
    ushort_t* X0hi = (ushort_t*)alloc((size_t)F * F * 2);
    ushort_t* X0lo = (ushort_t*)alloc((size_t)F * F * 2);
    ushort_t* X1hi = (ushort_t*)alloc((size_t)F * F * 2);
    ushort_t* X1lo = (ushort_t*)alloc((size_t)F * F * 2);
    ushort_t* Shi  = (ushort_t*)alloc((size_t)F * F * 2);
    ushort_t* Slo  = (ushort_t*)alloc((size_t)F * F * 2);
    float*    P    = (float*)alloc((size_t)36 * 8 * 16384 * 4);
    float*    v    = (float*)alloc(F * 4);
    float*    y    = (float*)alloc(F * 4);
    size_t need = off;

    if (ws_size >= need) {
        // ======== MFMA path ========
        tconv_kernel<<<dim3(16, 128), 256, 0, stream>>>(x, XThi, XTlo, part);
        finish_damp_kernel<<<1, 256, 0, stream>>>(part, scal);

        syrk_mfma_kernel<<<288, 256, 0, stream>>>(XThi, XTlo, P);
        reduceH_kernel<<<36 * 64, 256, 0, stream>>>(P, Hhi, Hlo, scal);

        init_v_kernel<<<4, 256, 0, stream>>>(v);
        for (int it = 0; it < 3; ++it) {
            matvec_bf16_kernel<<<F, 256, 0, stream>>>(Hhi, v, y);
            normalize_kernel<<<1, 256, 0, stream>>>(y, v, scal);
        }

        initX_kernel<<<(F * F) / 256, 256, 0, stream>>>(X0hi, X0lo, scal);

        ushort_t* xch = X0hi; ushort_t* xcl = X0lo;
        ushort_t* xnh = X1hi; ushort_t* xnl = X1lo;
        dim3 g(16, 16);
        for (int it = 0; it < 6; ++it) {
            bool last = (it == 5);
            if (it < 3) {
                ns_gemm_kernel<1, 0><<<g, 256, 0, stream>>>(xch, xcl, Hhi, Hlo,
                                                            nullptr, nullptr, Shi, Slo, nullptr);
                ns_gemm_kernel<1, 1><<<g, 256, 0, stream>>>(Shi, Slo, xch, xcl,
                                                            xch, xcl, xnh, xnl, nullptr);
            } else {
                ns_gemm_kernel<3, 0><<<g, 256, 0, stream>>>(xch, xcl, Hhi, Hlo,
                                                            nullptr, nullptr, Shi, Slo, nullptr);
                if (last)
                    ns_gemm_kernel<3, 2><<<g, 256, 0, stream>>>(Shi, Slo, xch, xcl,
                                                                xch, xcl, nullptr, nullptr, out);
                else
                    ns_gemm_kernel<3, 1><<<g, 256, 0, stream>>>(Shi, Slo, xch, xcl,
                                                                xch, xcl, xnh, xnl, nullptr);
            }
            ushort_t* th = xch; xch = xnh; xnh = th;
            ushort_t* tl = xcl; xcl = xnl; xnl = tl;
        }

        perm_kernel<<<4, 256, 0, stream>>>(out);
    } else {
        // ======== fp32 fallback ========
        float* ws = (float*)d_ws;
        float* fscal    = ws;
        float* fpartial = ws + 64;
        float* fH  = ws + 4096;
        float* fA  = fH + F * F;
        float* fB  = fA + F * F;
        float* fv  = fB + F * F;
        float* fy  = fv + F;
        float* R = out;

        sumsq_partial_kernel<<<2048, 256, 0, stream>>>(x, fpartial);
        finish_damp_kernel<<<1, 256, 0, stream>>>(fpartial, fscal);

        dim3 grid16(16, 16), blk16(16, 16);
        syrk_kernel<<<grid16, blk16, 0, stream>>>(x, fH, fscal);

        init_v_kernel<<<4, 256, 0, stream>>>(fv);
        for (int it = 0; it < 12; ++it) {
            matvec_kernel<<<F, 256, 0, stream>>>(fH, fv, fy);
            normalize_kernel<<<1, 256, 0, stream>>>(fy, fv, fscal);
        }

        init_X_kernel<<<(F * F) / 256, 256, 0, stream>>>(fA, fscal);
        float* Xc = fA;
        float* Xn = fB;
        for (int it = 0; it < 8; ++it) {
            gemm_nn_kernel<<<grid16, blk16, 0, stream>>>(fH, Xc, R, nullptr, 0);
            gemm_nn_kernel<<<grid16, blk16, 0, stream>>>(Xc, R, Xn, Xc, 1);
            float* tmp = Xc; Xc = Xn; Xn = tmp;
        }

        finalize_kernel<<<(F * F + F + 255) / 256, 256, 0, stream>>>(Xc, out);
    }
}

// Round 4
// 213.697 us; speedup vs baseline: 7.1686x; 1.1708x over previous
//
#include <hip/hip_runtime.h>
#include <math.h>

#define F 1024
#define NROWS 8192
#define NELEM (NROWS * F)

typedef unsigned short ushort_t;
typedef short bf16x8 __attribute__((ext_vector_type(8)));
typedef float f32x4 __attribute__((ext_vector_type(4)));
typedef unsigned short ushort8 __attribute__((ext_vector_type(8)));

__device__ __forceinline__ ushort_t f2bf(float f) {
  unsigned u = __float_as_uint(f);
  unsigned r = (u + 0x7fffu + ((u >> 16) & 1u)) >> 16;
  return (ushort_t)r;
}
__device__ __forceinline__ float bf2f(ushort_t b) {
  return __uint_as_float(((unsigned)b) << 16);
}

typedef const __attribute__((address_space(1))) unsigned int* gas_ptr;
typedef __attribute__((address_space(3))) unsigned int* las_ptr;
__device__ __forceinline__ void gload16(const void* g, const void* l) {
  __builtin_amdgcn_global_load_lds((gas_ptr)(unsigned long long)g,
                                   (las_ptr)(unsigned int)(unsigned long long)l,
                                   16, 0, 0);
}

// ---------------- tconv + fused sumsq ----------------
__global__ __launch_bounds__(256) void tconv_kernel(const float* __restrict__ x,
                                                    ushort_t* __restrict__ xthi,
                                                    ushort_t* __restrict__ xtlo,
                                                    float* __restrict__ partial) {
    __shared__ ushort_t th[64][68];
    __shared__ ushort_t tl[64][68];
    __shared__ float sdata[256];
    int c0 = blockIdx.x * 64;
    int r0 = blockIdx.y * 64;
    int tid = threadIdx.x;
    float ss = 0.f;
#pragma unroll
    for (int i = 0; i < 4; ++i) {
        int q = tid + 256 * i;
        int r = q >> 4;
        int cq = (q & 15) << 2;
        float4 vx = *(const float4*)&x[(size_t)(r0 + r) * 1024 + c0 + cq];
        float vv[4] = {vx.x, vx.y, vx.z, vx.w};
#pragma unroll
        for (int j = 0; j < 4; ++j) {
            ss = fmaf(vv[j], vv[j], ss);
            ushort_t h = f2bf(vv[j]);
            ushort_t l = f2bf(vv[j] - bf2f(h));
            th[r][cq + j] = h;
            tl[r][cq + j] = l;
        }
    }
    sdata[tid] = ss;
    __syncthreads();
    for (int off = 128; off > 0; off >>= 1) {
        if (tid < off) sdata[tid] += sdata[tid + off];
        __syncthreads();
    }
    if (tid == 0) partial[blockIdx.y * 16 + blockIdx.x] = sdata[0];
#pragma unroll
    for (int i = 0; i < 2; ++i) {
        int q = tid + 256 * i;
        int c = q >> 3;
        int rq = (q & 7) << 3;
        ushort8 oh, ol;
#pragma unroll
        for (int j = 0; j < 8; ++j) {
            oh[j] = th[rq + j][c];
            ol[j] = tl[rq + j][c];
        }
        *(ushort8*)&xthi[(size_t)(c0 + c) * 8192 + r0 + rq] = oh;
        *(ushort8*)&xtlo[(size_t)(c0 + c) * 8192 + r0 + rq] = ol;
    }
}

__global__ void finish_damp_kernel(const float* __restrict__ partial, float* __restrict__ scal) {
    __shared__ float sdata[256];
    int tid = threadIdx.x;
    float s = 0.f;
    for (int i = tid; i < 2048; i += 256) s += partial[i];
    sdata[tid] = s;
    __syncthreads();
    for (int off = 128; off > 0; off >>= 1) {
        if (tid < off) sdata[tid] += sdata[tid + off];
        __syncthreads();
    }
    if (tid == 0) {
        float mean = sdata[0] / (float)NELEM;
        scal[1] = 0.01f * mean;
    }
}

// ---------------- SYRK: triangle + z8, ring-4 LDS pipeline ----------------
__device__ __forceinline__ void stage128(const ushort_t* __restrict__ gp, int row0, int kk,
                                         ushort_t* sbase, int w, int lane) {
#pragma unroll
    for (int half = 0; half < 2; ++half) {
        int s = half * 256 + (w << 6) + lane;
        int r = s >> 2, pos = s & 3;
        int kc = (pos ^ ((r >> 1) & 3)) << 3;
        gload16(gp + (size_t)(row0 + r) * 8192 + kk + kc,
                sbase + (size_t)((half << 8) + (w << 6)) * 8);
    }
}

__global__ __launch_bounds__(256) void syrk_mfma_kernel(
    const ushort_t* __restrict__ XThi, const ushort_t* __restrict__ XTlo,
    float* __restrict__ P)
{
    __shared__ ushort_t smem[4 * 16384];   // ring-4, 128 KB
    int id = blockIdx.x;
    int z = id & 7, t = id >> 3;
    int bi = 0;
    while ((bi + 1) * (bi + 2) / 2 <= t) ++bi;
    int bj = t - bi * (bi + 1) / 2;
    int arow0 = bi * 128, brow0 = bj * 128;
    int k0 = z * 1024;

    int tid = threadIdx.x, lane = tid & 63, w = tid >> 6;
    int wm = w >> 1, wn = w & 1;
    int lr = lane & 15, cg = lane >> 4;

    f32x4 zero4 = {0.f, 0.f, 0.f, 0.f};
    f32x4 acc[4][4];
#pragma unroll
    for (int a = 0; a < 4; ++a)
#pragma unroll
        for (int b = 0; b < 4; ++b) acc[a][b] = zero4;

#define SYRK_STAGE(KT)                                                             \
    {                                                                              \
        ushort_t* sb = smem + (size_t)((KT) & 3) * 16384;                          \
        int kk = k0 + ((KT) << 5);                                                 \
        stage128(XThi, arow0, kk, sb + 0, w, lane);                                \
        stage128(XTlo, arow0, kk, sb + 4096, w, lane);                             \
        stage128(XThi, brow0, kk, sb + 8192, w, lane);                             \
        stage128(XTlo, brow0, kk, sb + 12288, w, lane);                            \
    }

#define SYRK_COMPUTE(KT)                                                           \
    {                                                                              \
        const ushort_t* sb = smem + (size_t)((KT) & 3) * 16384;                    \
        bf16x8 ah[4], bh[4], al[4], bl[4];                                         \
        _Pragma("unroll")                                                          \
        for (int fx = 0; fx < 4; ++fx) {                                           \
            int xo = (cg ^ ((lr >> 1) & 3)) << 3;                                  \
            int ao = ((wm << 6) + (fx << 4) + lr) * 32 + xo;                       \
            int bo = ((wn << 6) + (fx << 4) + lr) * 32 + xo;                       \
            ah[fx] = *(const bf16x8*)&sb[0 + ao];                                  \
            al[fx] = *(const bf16x8*)&sb[4096 + ao];                               \
            bh[fx] = *(const bf16x8*)&sb[8192 + bo];                               \
            bl[fx] = *(const bf16x8*)&sb[12288 + bo];                              \
        }                                                                          \
        _Pragma("unroll")                                                          \
        for (int fm = 0; fm < 4; ++fm)                                             \
            _Pragma("unroll")                                                      \
            for (int fn = 0; fn < 4; ++fn) {                                       \
                acc[fm][fn] = __builtin_amdgcn_mfma_f32_16x16x32_bf16(             \
                    ah[fm], bh[fn], acc[fm][fn], 0, 0, 0);                         \
                acc[fm][fn] = __builtin_amdgcn_mfma_f32_16x16x32_bf16(             \
                    ah[fm], bl[fn], acc[fm][fn], 0, 0, 0);                         \
                acc[fm][fn] = __builtin_amdgcn_mfma_f32_16x16x32_bf16(             \
                    al[fm], bh[fn], acc[fm][fn], 0, 0, 0);                         \
            }                                                                      \
    }

    SYRK_STAGE(0)
    SYRK_STAGE(1)
    SYRK_STAGE(2)
    for (int kt = 0; kt < 29; ++kt) {
        asm volatile("s_waitcnt vmcnt(16)" ::: "memory");
        __builtin_amdgcn_s_barrier();
        __builtin_amdgcn_sched_barrier(0);
        SYRK_STAGE(kt + 3)
        SYRK_COMPUTE(kt)
        __builtin_amdgcn_sched_barrier(0);
    }
    asm volatile("s_waitcnt vmcnt(16)" ::: "memory");
    __builtin_amdgcn_s_barrier();
    __builtin_amdgcn_sched_barrier(0);
    SYRK_COMPUTE(29)
    asm volatile("s_waitcnt vmcnt(8)" ::: "memory");
    __builtin_amdgcn_s_barrier();
    __builtin_amdgcn_sched_barrier(0);
    SYRK_COMPUTE(30)
    asm volatile("s_waitcnt vmcnt(0)" ::: "memory");
    __builtin_amdgcn_s_barrier();
    __builtin_amdgcn_sched_barrier(0);
    SYRK_COMPUTE(31)

    float* Pt = P + ((size_t)(t * 8 + z) << 14);
#pragma unroll
    for (int fm = 0; fm < 4; ++fm)
#pragma unroll
        for (int fn = 0; fn < 4; ++fn)
#pragma unroll
            for (int rr = 0; rr < 4; ++rr) {
                int row = (wm << 6) + fm * 16 + cg * 4 + rr;
                int col = (wn << 6) + fn * 16 + lr;
                Pt[row * 128 + col] = acc[fm][fn][rr];
            }
}

// ---------------- reduceH ----------------
__global__ void reduceH_kernel(const float* __restrict__ P,
                               ushort_t* __restrict__ Hhi, ushort_t* __restrict__ Hlo,
                               const float* __restrict__ scal) {
    int b = blockIdx.x;
    int tile = b >> 6;
    int li = ((b & 63) << 8) + threadIdx.x;
    int bi = 0;
    while ((bi + 1) * (bi + 2) / 2 <= tile) ++bi;
    int bj = tile - bi * (bi + 1) / 2;
    const float* Pt = P + ((size_t)tile << 17);
    float s = 0.f;
#pragma unroll
    for (int z = 0; z < 8; ++z) s += Pt[((size_t)z << 14) + li];
    int r = li >> 7, c = li & 127;
    int gi = bi * 128 + r, gj = bj * 128 + c;
    if (gi == gj) s += scal[1];
    ushort_t h = f2bf(s), l = f2bf(s - bf2f(h));
    Hhi[gi * F + gj] = h;
    Hlo[gi * F + gj] = l;
    if (bi != bj) {
        Hhi[gj * F + gi] = h;
        Hlo[gj * F + gi] = l;
    }
}

// ---------------- power iteration ----------------
__global__ void init_v_kernel(float* __restrict__ v) {
    int i = blockIdx.x * 256 + threadIdx.x;
    if (i < F) v[i] = 1.0f;
}

__global__ void matvec_bf16_kernel(const ushort_t* __restrict__ Hhi, const float* __restrict__ v,
                                   float* __restrict__ y) {
    __shared__ float sdata[256];
    int row = blockIdx.x, tid = threadIdx.x;
    float s = 0.f;
    for (int j = tid; j < F; j += 256) s = fmaf(bf2f(Hhi[row * F + j]), v[j], s);
    sdata[tid] = s;
    __syncthreads();
    for (int off = 128; off > 0; off >>= 1) {
        if (tid < off) sdata[tid] += sdata[tid + off];
        __syncthreads();
    }
    if (tid == 0) y[row] = sdata[0];
}

__global__ void normalize_kernel(const float* __restrict__ y, float* __restrict__ v,
                                 float* __restrict__ scal) {
    __shared__ float sdata[256];
    __shared__ float lam;
    int tid = threadIdx.x;
    float s = 0.f;
    for (int i = tid; i < F; i += 256) {
        float t = y[i];
        s = fmaf(t, t, s);
    }
    sdata[tid] = s;
    __syncthreads();
    for (int off = 128; off > 0; off >>= 1) {
        if (tid < off) sdata[tid] += sdata[tid + off];
        __syncthreads();
    }
    if (tid == 0) {
        lam = sqrtf(sdata[0]);
        scal[2] = lam;
        scal[3] = 1.0f / (1.05f * lam);
    }
    __syncthreads();
    float il = 1.0f / lam;
    for (int i = tid; i < F; i += 256) v[i] = y[i] * il;
}

// ---------------- init X0 = c*I ----------------
__global__ void initX_kernel(ushort_t* __restrict__ Xchi, ushort_t* __restrict__ Xclo,
                             const float* __restrict__ scal) {
    int idx = blockIdx.x * 256 + threadIdx.x;
    int i = idx >> 10, j = idx & (F - 1);
    float val = (i == j) ? scal[3] : 0.0f;
    ushort_t h = f2bf(val);
    Xchi[idx] = h;
    Xclo[idx] = f2bf(val - bf2f(h));
}

// ---------------- NS GEMM: 64x64 tile, K=1024, ring-4, fused epilogue ----------------
// slot layout (ushorts): Ahi@0, Bhi@2048, Alo@4096, Blo@6144; slot stride 8192 (t3) / 4096 (t1)
__device__ __forceinline__ void stage64(const ushort_t* __restrict__ gp, int row0, int kk,
                                        ushort_t* sbase, int tid) {
    int r = tid >> 2, pos = tid & 3;
    int kc = (pos ^ ((r >> 1) & 3)) << 3;
    gload16(gp + (size_t)(row0 + r) * 1024 + kk + kc, sbase + (size_t)(tid >> 6 << 9));
}

template <int TERMS, int MODE>
__global__ __launch_bounds__(256) void ns_gemm_kernel(
    const ushort_t* __restrict__ Ahi, const ushort_t* __restrict__ Alo,
    const ushort_t* __restrict__ Bhi, const ushort_t* __restrict__ Blo,
    const ushort_t* __restrict__ Xchi, const ushort_t* __restrict__ Xclo,
    ushort_t* __restrict__ Ohi, ushort_t* __restrict__ Olo,
    float* __restrict__ Of)
{
    constexpr int SLOT = (TERMS == 3) ? 8192 : 4096;
    __shared__ ushort_t smem[4 * SLOT];
    int tid = threadIdx.x, lane = tid & 63, w = tid >> 6;
    int wm = w >> 1, wn = w & 1;
    int row0 = blockIdx.y * 64, col0 = blockIdx.x * 64;
    int lr = lane & 15, cg = lane >> 4;

    f32x4 zero4 = {0.f, 0.f, 0.f, 0.f};
    f32x4 acc[2][2];
#pragma unroll
    for (int a = 0; a < 2; ++a)
#pragma unroll
        for (int b = 0; b < 2; ++b) acc[a][b] = zero4;

#define NS_STAGE(KT)                                                               \
    {                                                                              \
        ushort_t* sb = smem + (size_t)((KT) & 3) * SLOT;                           \
        int kk = (KT) << 5;                                                        \
        stage64(Ahi, row0, kk, sb + 0, tid);                                       \
        stage64(Bhi, col0, kk, sb + 2048, tid);                                    \
        if constexpr (TERMS == 3) {                                                \
            stage64(Alo, row0, kk, sb + 4096, tid);                                \
            stage64(Blo, col0, kk, sb + 6144, tid);                                \
        }                                                                          \
    }

#define NS_COMPUTE(KT)                                                             \
    {                                                                              \
        const ushort_t* sb = smem + (size_t)((KT) & 3) * SLOT;                     \
        bf16x8 ah[2], bh[2], al[2], bl[2];                                         \
        _Pragma("unroll")                                                          \
        for (int fx = 0; fx < 2; ++fx) {                                           \
            int xo = (cg ^ ((lr >> 1) & 3)) << 3;                                  \
            int ao = ((wm << 5) + (fx << 4) + lr) * 32 + xo;                       \
            int bo = ((wn << 5) + (fx << 4) + lr) * 32 + xo;                       \
            ah[fx] = *(const bf16x8*)&sb[0 + ao];                                  \
            bh[fx] = *(const bf16x8*)&sb[2048 + bo];                               \
            if constexpr (TERMS == 3) {                                            \
                al[fx] = *(const bf16x8*)&sb[4096 + ao];                           \
                bl[fx] = *(const bf16x8*)&sb[6144 + bo];                           \
            }                                                                      \
        }                                                                          \
        _Pragma("unroll")                                                          \
        for (int fm = 0; fm < 2; ++fm)                                             \
            _Pragma("unroll")                                                      \
            for (int fn = 0; fn < 2; ++fn) {                                       \
                acc[fm][fn] = __builtin_amdgcn_mfma_f32_16x16x32_bf16(             \
                    ah[fm], bh[fn], acc[fm][fn], 0, 0, 0);                         \
                if constexpr (TERMS == 3) {                                        \
                    acc[fm][fn] = __builtin_amdgcn_mfma_f32_16x16x32_bf16(         \
                        ah[fm], bl[fn], acc[fm][fn], 0, 0, 0);                     \
                    acc[fm][fn] = __builtin_amdgcn_mfma_f32_16x16x32_bf16(         \
                        al[fm], bh[fn], acc[fm][fn], 0, 0, 0);                     \
                }                                                                  \
            }                                                                      \
    }

#define NS_WAIT(N3, N1)                                                            \
    if constexpr (TERMS == 3) {                                                    \
        asm volatile("s_waitcnt vmcnt(" #N3 ")" ::: "memory");                     \
    } else {                                                                       \
        asm volatile("s_waitcnt vmcnt(" #N1 ")" ::: "memory");                     \
    }

    NS_STAGE(0)
    NS_STAGE(1)
    NS_STAGE(2)
    for (int kt = 0; kt < 29; ++kt) {
        NS_WAIT(8, 4)
        __builtin_amdgcn_s_barrier();
        __builtin_amdgcn_sched_barrier(0);
        NS_STAGE(kt + 3)
        NS_COMPUTE(kt)
        __builtin_amdgcn_sched_barrier(0);
    }
    NS_WAIT(8, 4)
    __builtin_amdgcn_s_barrier();
    __builtin_amdgcn_sched_barrier(0);
    NS_COMPUTE(29)
    NS_WAIT(4, 2)
    __builtin_amdgcn_s_barrier();
    __builtin_amdgcn_sched_barrier(0);
    NS_COMPUTE(30)
    NS_WAIT(0, 0)
    __builtin_amdgcn_s_barrier();
    __builtin_amdgcn_sched_barrier(0);
    NS_COMPUTE(31)

#pragma unroll
    for (int fm = 0; fm < 2; ++fm)
#pragma unroll
        for (int fn = 0; fn < 2; ++fn)
#pragma unroll
            for (int rr = 0; rr < 4; ++rr) {
                int r = row0 + (wm << 5) + fm * 16 + cg * 4 + rr;
                int c = col0 + (wn << 5) + fn * 16 + lr;
                size_t idx = (size_t)r * F + c;
                float val = acc[fm][fn][rr];
                if constexpr (MODE == 0) {
                    ushort_t h = f2bf(val);
                    Ohi[idx] = h;
                    Olo[idx] = f2bf(val - bf2f(h));
                } else {
                    float xc = bf2f(Xchi[idx]) + bf2f(Xclo[idx]);
                    val = 2.0f * xc - val;
                    if constexpr (MODE == 1) {
                        ushort_t h = f2bf(val);
                        Ohi[idx] = h;
                        Olo[idx] = f2bf(val - bf2f(h));
                    } else {
                        Of[idx] = val;
                    }
                }
            }
}

// ---------------- perm tail ----------------
__global__ void perm_kernel(float* __restrict__ out) {
    int i = blockIdx.x * 256 + threadIdx.x;
    if (i < F) out[(size_t)F * F + i] = (float)i;
}

// ======================= fp32 fallback path =======================
__global__ void sumsq_partial_kernel(const float* __restrict__ x, float* __restrict__ partial) {
    __shared__ float sdata[256];
    int tid = threadIdx.x;
    int base = blockIdx.x * 4096;
    float s = 0.f;
    for (int i = tid; i < 4096; i += 256) {
        float v = x[base + i];
        s = fmaf(v, v, s);
    }
    sdata[tid] = s;
    __syncthreads();
    for (int off = 128; off > 0; off >>= 1) {
        if (tid < off) sdata[tid] += sdata[tid + off];
        __syncthreads();
    }
    if (tid == 0) partial[blockIdx.x] = sdata[0];
}

__global__ void matvec_kernel(const float* __restrict__ H, const float* __restrict__ v,
                              float* __restrict__ y) {
    __shared__ float sdata[256];
    int row = blockIdx.x, tid = threadIdx.x;
    float s = 0.f;
    for (int j = tid; j < F; j += 256) s = fmaf(H[row * F + j], v[j], s);
    sdata[tid] = s;
    __syncthreads();
    for (int off = 128; off > 0; off >>= 1) {
        if (tid < off) sdata[tid] += sdata[tid + off];
        __syncthreads();
    }
    if (tid == 0) y[row] = sdata[0];
}

__global__ __launch_bounds__(256) void syrk_kernel(const float* __restrict__ X,
                                                   float* __restrict__ H,
                                                   const float* __restrict__ scal) {
    __shared__ float LA[16][64];
    __shared__ float LB[16][64];
    int tx = threadIdx.x, ty = threadIdx.y;
    int t = ty * 16 + tx;
    int i0 = blockIdx.y * 64, j0 = blockIdx.x * 64;
    int lk = t >> 4;
    int lc = (t & 15) << 2;
    float acc[4][4] = {};
    for (int k0 = 0; k0 < NROWS; k0 += 16) {
        int r = (k0 + lk) * F;
        float4 a4 = *(const float4*)&X[r + i0 + lc];
        float4 b4 = *(const float4*)&X[r + j0 + lc];
        __syncthreads();
        *(float4*)&LA[lk][lc] = a4;
        *(float4*)&LB[lk][lc] = b4;
        __syncthreads();
#pragma unroll
        for (int kk = 0; kk < 16; ++kk) {
            float4 a = *(const float4*)&LA[kk][ty << 2];
            float4 b = *(const float4*)&LB[kk][tx << 2];
            float av[4] = {a.x, a.y, a.z, a.w};
            float bv[4] = {b.x, b.y, b.z, b.w};
#pragma unroll
            for (int rr = 0; rr < 4; ++rr)
#pragma unroll
                for (int cc = 0; cc < 4; ++cc)
                    acc[rr][cc] = fmaf(av[rr], bv[cc], acc[rr][cc]);
        }
    }
    float damp = scal[1];
#pragma unroll
    for (int rr = 0; rr < 4; ++rr) {
        int i = i0 + (ty << 2) + rr;
#pragma unroll
        for (int cc = 0; cc < 4; ++cc) {
            int j = j0 + (tx << 2) + cc;
            float v = acc[rr][cc];
            if (i == j) v += damp;
            H[i * F + j] = v;
        }
    }
}

__global__ void init_X_kernel(float* __restrict__ A, const float* __restrict__ scal) {
    int idx = blockIdx.x * 256 + threadIdx.x;
    int i = idx >> 10, j = idx & (F - 1);
    A[idx] = (i == j) ? scal[3] : 0.0f;
}

__global__ __launch_bounds__(256) void gemm_nn_kernel(const float* __restrict__ A,
                                                      const float* __restrict__ Bm,
                                                      float* __restrict__ C,
                                                      const float* __restrict__ D,
                                                      int mode) {
    __shared__ float LA[16][64];
    __shared__ float LB[16][64];
    int tx = threadIdx.x, ty = threadIdx.y;
    int t = ty * 16 + tx;
    int i0 = blockIdx.y * 64, j0 = blockIdx.x * 64;
    int aii = t >> 2;
    int akq = (t & 3) << 2;
    int bkk = t >> 4;
    int bjq = (t & 15) << 2;
    float acc[4][4] = {};
    for (int k0 = 0; k0 < F; k0 += 16) {
        float4 a4 = *(const float4*)&A[(i0 + aii) * F + k0 + akq];
        float4 b4 = *(const float4*)&Bm[(k0 + bkk) * F + j0 + bjq];
        __syncthreads();
        LA[akq + 0][aii] = a4.x;
        LA[akq + 1][aii] = a4.y;
        LA[akq + 2][aii] = a4.z;
        LA[akq + 3][aii] = a4.w;
        *(float4*)&LB[bkk][bjq] = b4;
        __syncthreads();
#pragma unroll
        for (int kk = 0; kk < 16; ++kk) {
            float4 a = *(const float4*)&LA[kk][ty << 2];
            float4 b = *(const float4*)&LB[kk][tx << 2];
            float av[4] = {a.x, a.y, a.z, a.w};
            float bv[4] = {b.x, b.y, b.z, b.w};
#pragma unroll
            for (int rr = 0; rr < 4; ++rr)
#pragma unroll
                for (int cc = 0; cc < 4; ++cc)
                    acc[rr][cc] = fmaf(av[rr], bv[cc], acc[rr][cc]);
        }
    }
#pragma unroll
    for (int rr = 0; rr < 4; ++rr) {
        int i = i0 + (ty << 2) + rr;
#pragma unroll
        for (int cc = 0; cc < 4; ++cc) {
            int j = j0 + (tx << 2) + cc;
            float v = acc[rr][cc];
            if (mode == 1) v = 2.0f * D[i * F + j] - v;
            C[i * F + j] = v;
        }
    }
}

__global__ void finalize_kernel(const float* __restrict__ A, float* __restrict__ out) {
    int idx = blockIdx.x * 256 + threadIdx.x;
    if (idx < F * F) out[idx] = A[idx];
    else if (idx < F * F + F) out[idx] = (float)(idx - F * F);
}

// ======================= launch =======================
extern "C" void kernel_launch(void* const* d_in, const int* in_sizes, int n_in,
                              void* d_out, int out_size, void* d_ws, size_t ws_size,
                              hipStream_t stream) {
    const float* x = (const float*)d_in[0];
    float* out = (float*)d_out;

    char* base = (char*)d_ws;
    size_t off = 0;
    auto alloc = [&](size_t bytes) -> char* {
        char* p = base + off;
        off += bytes;
        off = (off + 255) & ~(size_t)255;
        return p;
    };
    float*    scal = (float*)alloc(64 * 4);
    float*    part = (float*)alloc(2048 * 4);
    ushort_t* XThi = (ushort_t*)alloc((size_t)NELEM * 2);
    ushort_t* XTlo = (ushort_t*)alloc((size_t)NELEM * 2);
    ushort_t* Hhi  = (ushort_t*)alloc((size_t)F * F * 2);
    ushort_t* Hlo  = (ushort_t*)alloc((size_t)F * F * 2);
    ushort_t* X0hi = (ushort_t*)alloc((size_t)F * F * 2);
    ushort_t* X0lo = (ushort_t*)alloc((size_t)F * F * 2);
    ushort_t* X1hi = (ushort_t*)alloc((size_t)F * F * 2);
    ushort_t* X1lo = (ushort_t*)alloc((size_t)F * F * 2);
    ushort_t* Shi  = (ushort_t*)alloc((size_t)F * F * 2);
    ushort_t* Slo  = (ushort_t*)alloc((size_t)F * F * 2);
    float*    P    = (float*)alloc((size_t)36 * 8 * 16384 * 4);
    float*    v    = (float*)alloc(F * 4);
    float*    y    = (float*)alloc(F * 4);
    size_t need = off;

    if (ws_size >= need) {
        // ======== MFMA path ========
        tconv_kernel<<<dim3(16, 128), 256, 0, stream>>>(x, XThi, XTlo, part);
        finish_damp_kernel<<<1, 256, 0, stream>>>(part, scal);

        syrk_mfma_kernel<<<288, 256, 0, stream>>>(XThi, XTlo, P);
        reduceH_kernel<<<36 * 64, 256, 0, stream>>>(P, Hhi, Hlo, scal);

        init_v_kernel<<<4, 256, 0, stream>>>(v);
        for (int it = 0; it < 2; ++it) {
            matvec_bf16_kernel<<<F, 256, 0, stream>>>(Hhi, v, y);
            normalize_kernel<<<1, 256, 0, stream>>>(y, v, scal);
        }

        initX_kernel<<<(F * F) / 256, 256, 0, stream>>>(X0hi, X0lo, scal);

        ushort_t* xch = X0hi; ushort_t* xcl = X0lo;
        ushort_t* xnh = X1hi; ushort_t* xnl = X1lo;
        dim3 g(16, 16);
        for (int it = 0; it < 5; ++it) {
            bool last = (it == 4);
            if (it < 2) {
                ns_gemm_kernel<1, 0><<<g, 256, 0, stream>>>(xch, xcl, Hhi, Hlo,
                                                            nullptr, nullptr, Shi, Slo, nullptr);
                ns_gemm_kernel<1, 1><<<g, 256, 0, stream>>>(Shi, Slo, xch, xcl,
                                                            xch, xcl, xnh, xnl, nullptr);
            } else {
                ns_gemm_kernel<3, 0><<<g, 256, 0, stream>>>(xch, xcl, Hhi, Hlo,
                                                            nullptr, nullptr, Shi, Slo, nullptr);
                if (last)
                    ns_gemm_kernel<3, 2><<<g, 256, 0, stream>>>(Shi, Slo, xch, xcl,
                                                                xch, xcl, nullptr, nullptr, out);
                else
                    ns_gemm_kernel<3, 1><<<g, 256, 0, stream>>>(Shi, Slo, xch, xcl,
                                                                xch, xcl, xnh, xnl, nullptr);
            }
            ushort_t* th = xch; xch = xnh; xnh = th;
            ushort_t* tl = xcl; xcl = xnl; xnl = tl;
        }

        perm_kernel<<<4, 256, 0, stream>>>(out);
    } else {
        // ======== fp32 fallback ========
        float* ws = (float*)d_ws;
        float* fscal    = ws;
        float* fpartial = ws + 64;
        float* fH  = ws + 4096;
        float* fA  = fH + F * F;
        float* fB  = fA + F * F;
        float* fv  = fB + F * F;
        float* fy  = fv + F;
        float* R = out;

        sumsq_partial_kernel<<<2048, 256, 0, stream>>>(x, fpartial);
        finish_damp_kernel<<<1, 256, 0, stream>>>(fpartial, fscal);

        dim3 grid16(16, 16), blk16(16, 16);
        syrk_kernel<<<grid16, blk16, 0, stream>>>(x, fH, fscal);

        init_v_kernel<<<4, 256, 0, stream>>>(fv);
        for (int it = 0; it < 12; ++it) {
            matvec_kernel<<<F, 256, 0, stream>>>(fH, fv, fy);
            normalize_kernel<<<1, 256, 0, stream>>>(fy, fv, fscal);
        }

        init_X_kernel<<<(F * F) / 256, 256, 0, stream>>>(fA, fscal);
        float* Xc = fA;
        float* Xn = fB;
        for (int it = 0; it < 8; ++it) {
            gemm_nn_kernel<<<grid16, blk16, 0, stream>>>(fH, Xc, R, nullptr, 0);
            gemm_nn_kernel<<<grid16, blk16, 0, stream>>>(Xc, R, Xn, Xc, 1);
            float* tmp = Xc; Xc = Xn; Xn = tmp;
        }

        finalize_kernel<<<(F * F + F + 255) / 256, 256, 0, stream>>>(Xc, out);
    }
}